// Round 5
// baseline (67.315 us; speedup 1.0000x reference)
//
#include <hip/hip_runtime.h>
#include <math.h>

#define DIM 1280
#define COL4 320            // DIM/4 float4-columns per row
#define NT 320              // block = one row's worth of float4 columns (5 waves)
#define GRID 1536           // 1536 blocks * 5 waves = 7680 waves = 30/CU: ALL resident, no tail

typedef float f32x4 __attribute__((ext_vector_type(4)));

// out[b][i] = i%2==0 ? sin(time[b]*rate(i)) : cos(time[b]*rate(i))
// rate(i) = 10000^(-(i//2)/640) = exp2(-(i//2) * log2(10000)/640)
__global__ __launch_bounds__(NT)
void time_emb_kernel(const float* __restrict__ time, f32x4* __restrict__ out4, int total4) {
    const int col4 = threadIdx.x;        // fixed column for the whole kernel
    int b = blockIdx.x;                  // row; advances by GRID per iter

    const float L_over_640 = 13.287712379549449f / 640.0f;  // log2(10000)/640
    const float rate0 = exp2f(-(float)(2 * col4)     * L_over_640);
    const float rate1 = exp2f(-(float)(2 * col4 + 1) * L_over_640);

    #pragma unroll 4
    for (int idx = blockIdx.x * NT + threadIdx.x; idx < total4;
         idx += GRID * NT, b += GRID) {
        const float tv = time[b];        // wave-uniform, L2-resident
        float s0, c0, s1, c1;
        __sincosf(tv * rate0, &s0, &c0);
        __sincosf(tv * rate1, &s1, &c1);
        f32x4 v; v.x = s0; v.y = c0; v.z = s1; v.w = c1;
        out4[idx] = v;                   // block writes one contiguous 5120B row per iter
    }
}

extern "C" void kernel_launch(void* const* d_in, const int* in_sizes, int n_in,
                              void* d_out, int out_size, void* d_ws, size_t ws_size,
                              hipStream_t stream) {
    const float* time = (const float*)d_in[0];
    f32x4* out4 = (f32x4*)d_out;
    const int batch = in_sizes[0];       // 65536
    const int total4 = batch * COL4;     // 20,971,520 float4s

    time_emb_kernel<<<GRID, NT, 0, stream>>>(time, out4, total4);
}

// Round 6
// 65.196 us; speedup vs baseline: 1.0325x; 1.0325x over previous
//
#include <hip/hip_runtime.h>
#include <math.h>

#define DIM 1280
#define COL4 320            // DIM/4 float4-columns per row
#define NT 256
#define GRID 2560           // GRID*NT = 655360 = 320*2048 -> stride keeps col fixed, b += 2048

typedef float f32x4 __attribute__((ext_vector_type(4)));

// out[b][i] = i%2==0 ? sin(time[b]*rate(i)) : cos(time[b]*rate(i))
// rate(i) = 10000^(-(i//2)/640) = exp2(-(i//2) * log2(10000)/640)
__global__ __launch_bounds__(NT)
void time_emb_kernel(const float* __restrict__ time, f32x4* __restrict__ out4, int total4) {
    const int tid = blockIdx.x * NT + threadIdx.x;   // flat float4 index, iter 0
    const int col4 = tid % COL4;                     // fixed per thread across iters
    int b = tid / COL4;                              // row; advances by +2048 per iter

    const float L_over_640 = 13.287712379549449f / 640.0f;  // log2(10000)/640
    const float rate0 = exp2f(-(float)(2 * col4)     * L_over_640);
    const float rate1 = exp2f(-(float)(2 * col4 + 1) * L_over_640);

    #pragma unroll 4
    for (int idx = tid; idx < total4; idx += GRID * NT, b += 2048) {
        const float tv = time[b];                    // L1/L2-resident (256 KB total)
        float s0, c0, s1, c1;
        __sincosf(tv * rate0, &s0, &c0);
        __sincosf(tv * rate1, &s1, &c1);
        f32x4 v; v.x = s0; v.y = c0; v.z = s1; v.w = c1;
        // write-once stream > L3: bypass cache allocation
        __builtin_nontemporal_store(v, &out4[idx]);
    }
}

extern "C" void kernel_launch(void* const* d_in, const int* in_sizes, int n_in,
                              void* d_out, int out_size, void* d_ws, size_t ws_size,
                              hipStream_t stream) {
    const float* time = (const float*)d_in[0];
    f32x4* out4 = (f32x4*)d_out;
    const int batch = in_sizes[0];                   // 65536
    const int total4 = batch * COL4;                 // 20,971,520 float4s

    time_emb_kernel<<<GRID, NT, 0, stream>>>(time, out4, total4);
}